// Round 7
// baseline (569.586 us; speedup 1.0000x reference)
//
#include <hip/hip_runtime.h>

typedef __attribute__((ext_vector_type(8))) short bf16x8;
typedef __attribute__((ext_vector_type(4))) float f32x4;

#define WS_QKV   0          // 384 KiB: qkv frags (48 rt * 8 ks * 1024B), q-rows prescaled
#define WS_PROJ  393216     // 128 KiB: proj frags (16 rt * 8 ks * 1024B)
#define WS_MB    524288     // 8 MiB: mb[w][h][64][64] f32 = (mask[w]+bias[h])*log2e
#define WS_QB    8912896    // 3 KiB: qkvb_s[768] (q part prescaled by scale*log2e)

#define QSCALE 0.17677669529663687f   // 1/sqrt(32)
#define LOG2E  1.4426950408889634f

__device__ __forceinline__ unsigned short f2bf(float f) {
  unsigned u = __builtin_bit_cast(unsigned, f);
  u += 0x7FFFu + ((u >> 16) & 1u);
  return (unsigned short)(u >> 16);
}

__device__ __forceinline__ unsigned long long pack4bf(f32x4 v) {
  unsigned long long r0 = f2bf(v[0]);
  unsigned long long r1 = f2bf(v[1]);
  unsigned long long r2 = f2bf(v[2]);
  unsigned long long r3 = f2bf(v[3]);
  return r0 | (r1 << 16) | (r2 << 32) | (r3 << 48);
}

// frag(rt,ks): lane l holds W[16*rt + (l&15)][32*ks + 8*(l>>4) + i], i=0..7 (bf16)
__global__ void prep_weights(const float* __restrict__ qkv_w,
                             const float* __restrict__ proj_w,
                             unsigned char* __restrict__ ws) {
  int g = blockIdx.x;   // 0..511
  int l = threadIdx.x;  // 0..63
  int lr = l & 15, lg = l >> 4;
  const float* src;
  float sc = 1.f;
  if (g < 384) {
    int rt = g >> 3, ks = g & 7;
    src = qkv_w + (size_t)(16 * rt + lr) * 256 + 32 * ks + 8 * lg;
    if (rt < 16) sc = QSCALE * LOG2E;  // fold scale and log2e into q rows
  } else {
    int p = g - 384;
    int rt = p >> 3, ks = p & 7;
    src = proj_w + (size_t)(16 * rt + lr) * 256 + 32 * ks + 8 * lg;
  }
  f32x4 a = *(const f32x4*)(src)*sc;
  f32x4 b = *(const f32x4*)(src + 4) * sc;
  unsigned long long* dst = (unsigned long long*)(ws + (size_t)g * 1024 + l * 16);
  dst[0] = pack4bf(a);
  dst[1] = pack4bf(b);
}

// mb[w][h][64][64] = (mask + rel-pos bias) * log2e, masked cols -> -1e30
__global__ void prep_aux(const float* __restrict__ mask,
                         const float* __restrict__ bias_table,
                         const float* __restrict__ qkv_b,
                         unsigned char* __restrict__ ws) {
  int bid = blockIdx.x, tid = threadIdx.x;
  if (bid < 512) {
    int w = bid >> 3, h = bid & 7;
    float* dst = (float*)(ws + WS_MB) + (size_t)bid * 4096;
    for (int it = 0; it < 16; ++it) {
      int idx = it * 256 + tid;
      int m = idx >> 6, j = idx & 63;
      float v;
      if (j >= 49) {
        v = -1e30f;
      } else {
        float bi = 0.f, mk = 0.f;
        if (m < 49) {
          int rm = m / 7, cm = m % 7, rj = j / 7, cj = j % 7;
          int rpi = (rm - rj + 6) * 13 + (cm - cj + 6);
          bi = bias_table[rpi * 8 + h];
          mk = mask[((size_t)w * 49 + m) * 49 + j];
        }
        v = (mk + bi) * LOG2E;
      }
      dst[idx] = v;
    }
  } else {  // qkv bias: q part prescaled
    float* dst = (float*)(ws + WS_QB);
    for (int i = tid; i < 768; i += 256)
      dst[i] = qkv_b[i] * (i < 256 ? QSCALE * LOG2E : 1.f);
  }
}

// One block = one window, 8 waves (512 thr), 2 passes of 4 heads.
// Wave wv: head-slot hs = wv>>1, m-half s = wv&1; pass p: head h = 4p + hs.
// LDS 77 KiB -> 2 blocks/CU; __launch_bounds__(512,4) caps total regs at 128.
//  [0,32K)        xs: bf16 x[64][256], byte(r,c) = r*512 + ((2c)^((r&7)<<4));
//                 reused as ao[m][256ch] in the epilogue (same swizzle)
//  head-slot hs:  bufQ = 32768 + hs*9216  (q [64m][32d] stride 72; later
//                   vT [32d][64tok] stride 128, byte = d*128+((2t)^((d&7)<<4)))
//                 bufK = bufQ + 4608      (k [64m][32d] stride 72 — intact
//                   through the v-pass, kf read AFTER it: cuts reg pressure)
//  per wave:      bufP = 69632 + wv*1152  ([16m][32j] stride 72)
__global__ __launch_bounds__(512, 4)
void winattn_main(const float* __restrict__ x,
                  const unsigned char* __restrict__ ws,
                  const float* __restrict__ proj_b,
                  float* __restrict__ out) {
  __shared__ __align__(16) unsigned char lds[78848];
  const int tid = threadIdx.x;
  const int wv = tid >> 6, ln = tid & 63;
  const int lr = ln & 15, lg = ln >> 4;
  const int b = blockIdx.x;
  const int w = b & 63;
  const int hs = wv >> 1, s = wv & 1;
  const float* qbs = (const float*)(ws + WS_QB);
  unsigned char* bufQ = lds + 32768 + hs * 9216;  // q, then vT
  unsigned char* bufK = bufQ + 4608;
  unsigned char* bufP = lds + 69632 + wv * 1152;

  // ---- stage x -> xs (bf16, swizzled), rows >= 49 zeroed
  {
    const int r = tid >> 3;
    const int c0 = (tid & 7) * 4;
    const float* xrow = x + ((size_t)b * 49 + r) * 256;
    unsigned char* row = lds + r * 512;
    const int swz = (r & 7) << 4;
#pragma unroll
    for (int u = 0; u < 8; ++u) {
      int c = c0 + 32 * u;
      f32x4 v = {0.f, 0.f, 0.f, 0.f};
      if (r < 49) v = *(const f32x4*)(xrow + c);
      *(unsigned long long*)(row + ((2 * c) ^ swz)) = pack4bf(v);
    }
  }
  __syncthreads();

  unsigned long long aoPk[2][2][2];  // [pass][dt][i] packed bf16x4 (8 VGPRs)

#pragma unroll
  for (int p = 0; p < 2; ++p) {
    if (p) __syncthreads();  // bufQ/bufK reuse: pass1's vf/kf reads done
    const int h = 4 * p + hs;
    const float* mbp = (const float*)(ws + WS_MB) + ((size_t)(w * 8 + h)) * 4096;

    // ---- Phase B: q, k, v GEMMs (wave pair splits token tiles)
    bf16x8 qf[2], kf[4];
#pragma unroll
    for (int pp = 0; pp < 3; ++pp) {  // 0=q, 1=k, 2=v
      const int rtb = (pp == 0 ? 0 : (pp == 1 ? 16 : 32)) + 2 * h;
      bf16x8 af0[8], af1[8];
#pragma unroll
      for (int ks = 0; ks < 8; ++ks) {
        af0[ks] = *(const bf16x8*)(ws + (size_t)(rtb * 8 + ks) * 1024 + ln * 16);
        af1[ks] = *(const bf16x8*)(ws + (size_t)((rtb + 1) * 8 + ks) * 1024 + ln * 16);
      }
      f32x4 c0, c1;
      if (pp < 2) {
        c0 = *(const f32x4*)(qbs + pp * 256 + 32 * h + 4 * lg);
        c1 = *(const f32x4*)(qbs + pp * 256 + 32 * h + 16 + 4 * lg);
      } else {
        float vb0 = qbs[512 + 32 * h + lr];
        float vb1 = qbs[512 + 32 * h + 16 + lr];
        c0 = {vb0, vb0, vb0, vb0};
        c1 = {vb1, vb1, vb1, vb1};
      }
#pragma unroll
      for (int ti = 0; ti < 2; ++ti) {
        const int t = 2 * s + ti;
        const int row = 16 * t + lr;
        const unsigned char* rp = lds + row * 512;
        const int swz = (row & 7) << 4;
        bf16x8 xfr[8];
#pragma unroll
        for (int ks = 0; ks < 8; ++ks)
          xfr[ks] = *(const bf16x8*)(rp + ((64 * ks + 16 * lg) ^ swz));
        f32x4 a0 = c0, a1 = c1;
        if (pp < 2) {
          // D[ch][tok]: col = tok = 16t+lr, rows = ch
#pragma unroll
          for (int ks = 0; ks < 8; ++ks) {
            a0 = __builtin_amdgcn_mfma_f32_16x16x32_bf16(af0[ks], xfr[ks], a0, 0, 0, 0);
            a1 = __builtin_amdgcn_mfma_f32_16x16x32_bf16(af1[ks], xfr[ks], a1, 0, 0, 0);
          }
          unsigned char* dst = (pp == 0 ? bufQ : bufK);
          *(unsigned long long*)(dst + row * 72 + 8 * lg) = pack4bf(a0);
          *(unsigned long long*)(dst + row * 72 + 32 + 8 * lg) = pack4bf(a1);
        } else {
          // D[tok][d]: col = d, rows = tok -> vT[d][tok] into bufQ (q consumed)
#pragma unroll
          for (int ks = 0; ks < 8; ++ks) {
            a0 = __builtin_amdgcn_mfma_f32_16x16x32_bf16(xfr[ks], af0[ks], a0, 0, 0, 0);
            a1 = __builtin_amdgcn_mfma_f32_16x16x32_bf16(xfr[ks], af1[ks], a1, 0, 0, 0);
          }
          const int tb = 32 * t + 8 * lg;
          *(unsigned long long*)(bufQ + lr * 128 + (tb ^ ((lr & 7) << 4))) = pack4bf(a0);
          *(unsigned long long*)(bufQ + (16 + lr) * 128 + (tb ^ ((lr & 7) << 4))) = pack4bf(a1);
        }
      }
      if (pp == 0) {
        // own half only -> no barrier needed
#pragma unroll
        for (int i = 0; i < 2; ++i)
          qf[i] = *(const bf16x8*)(bufQ + (lr + 32 * s + 16 * i) * 72 + 16 * lg);
      }
    }
    __syncthreads();  // k and vT fully staged (cross-wave within the pair)
#pragma unroll
    for (int t = 0; t < 4; ++t)
      kf[t] = *(const bf16x8*)(bufK + (lr + 16 * t) * 72 + 16 * lg);

    // ---- Phase C: S^T = K Q^T (C-init = mb), exp2 softmax (no max-sub),
    //      online over j-halves; normalization deferred.
    float sm[2] = {0.f, 0.f};
    f32x4 oacc[2][2];
#pragma unroll
    for (int dt = 0; dt < 2; ++dt)
#pragma unroll
      for (int i = 0; i < 2; ++i) oacc[dt][i] = {0.f, 0.f, 0.f, 0.f};

#pragma unroll
    for (int jh = 0; jh < 2; ++jh) {
      f32x4 s2[2][2];
#pragma unroll
      for (int jt2 = 0; jt2 < 2; ++jt2) {
        const int jt = 2 * jh + jt2;
#pragma unroll
        for (int i = 0; i < 2; ++i) {
          const int m = lr + 32 * s + 16 * i;
          f32x4 mk = *(const f32x4*)(mbp + m * 64 + 16 * jt + 4 * lg);
          s2[jt2][i] = __builtin_amdgcn_mfma_f32_16x16x32_bf16(kf[jt], qf[i], mk, 0, 0, 0);
#pragma unroll
          for (int r2 = 0; r2 < 4; ++r2) {
            float e = __builtin_amdgcn_exp2f(s2[jt2][i][r2]);
            s2[jt2][i][r2] = e;
            sm[i] += e;
          }
        }
      }
      bf16x8 vf[2];
#pragma unroll
      for (int dt = 0; dt < 2; ++dt) {
        const int d = lr + 16 * dt;
        vf[dt] = *(const bf16x8*)(bufQ + d * 128 + ((64 * jh + 16 * lg) ^ ((d & 7) << 4)));
      }
#pragma unroll
      for (int i = 0; i < 2; ++i) {
#pragma unroll
        for (int jt2 = 0; jt2 < 2; ++jt2)
          *(unsigned long long*)(bufP + lr * 72 + 32 * jt2 + 8 * lg) = pack4bf(s2[jt2][i]);
        bf16x8 pf = *(const bf16x8*)(bufP + lr * 72 + 16 * lg);
#pragma unroll
        for (int dt = 0; dt < 2; ++dt)
          oacc[dt][i] = __builtin_amdgcn_mfma_f32_16x16x32_bf16(vf[dt], pf, oacc[dt][i], 0, 0, 0);
      }
    }
#pragma unroll
    for (int i = 0; i < 2; ++i) {
      float t = sm[i];
      t += __shfl_xor(t, 16);
      t += __shfl_xor(t, 32);
      float inv = 1.f / t;
#pragma unroll
      for (int dt = 0; dt < 2; ++dt) aoPk[p][dt][i] = pack4bf(oacc[dt][i] * inv);
    }
  }

  __syncthreads();  // all attention done; xs reads (pass-2 xfr) done

  // ao[m][256] into xs region: head h owns bytes [64h, 64h+64) per row
#pragma unroll
  for (int p = 0; p < 2; ++p) {
    const int h = 4 * p + hs;
#pragma unroll
    for (int dt = 0; dt < 2; ++dt)
#pragma unroll
      for (int i = 0; i < 2; ++i) {
        const int m = lr + 32 * s + 16 * i;
        *(unsigned long long*)(lds + m * 512 +
                               ((64 * h + 32 * dt + 8 * lg) ^ ((m & 7) << 4))) =
            aoPk[p][dt][i];
      }
  }
  __syncthreads();

  // ---- Phase D: proj^T[o][m] = sum_c Wp[o][c] * ao[m][c]
  const unsigned char* wsP = ws + WS_PROJ;
#pragma unroll
  for (int tt = 0; tt < 4; ++tt) {
    const int m = lr + 16 * tt;
    bf16x8 aof[8];
#pragma unroll
    for (int ks = 0; ks < 8; ++ks)
      aof[ks] = *(const bf16x8*)(lds + m * 512 + ((64 * ks + 16 * lg) ^ ((m & 7) << 4)));
#pragma unroll
    for (int i2 = 0; i2 < 2; ++i2) {
      const int mt = 2 * wv + i2;
      bf16x8 af[8];
#pragma unroll
      for (int ks = 0; ks < 8; ++ks)
        af[ks] = *(const bf16x8*)(wsP + (size_t)(mt * 8 + ks) * 1024 + ln * 16);
      f32x4 acc = {0.f, 0.f, 0.f, 0.f};
#pragma unroll
      for (int ks = 0; ks < 8; ++ks)
        acc = __builtin_amdgcn_mfma_f32_16x16x32_bf16(af[ks], aof[ks], acc, 0, 0, 0);
      if (m < 49) {
        f32x4 pb = *(const f32x4*)(proj_b + 16 * mt + 4 * lg);
        acc += pb;
        *(f32x4*)(out + ((size_t)b * 49 + m) * 256 + 16 * mt + 4 * lg) = acc;
      }
    }
  }
}

extern "C" void kernel_launch(void* const* d_in, const int* in_sizes, int n_in,
                              void* d_out, int out_size, void* d_ws, size_t ws_size,
                              hipStream_t stream) {
  const float* x = (const float*)d_in[0];
  const float* mask = (const float*)d_in[1];
  const float* qkv_w = (const float*)d_in[2];
  const float* qkv_b = (const float*)d_in[3];
  const float* proj_w = (const float*)d_in[4];
  const float* proj_b = (const float*)d_in[5];
  const float* bias_table = (const float*)d_in[6];
  unsigned char* ws = (unsigned char*)d_ws;
  float* out = (float*)d_out;

  prep_weights<<<512, 64, 0, stream>>>(qkv_w, proj_w, ws);
  prep_aux<<<513, 256, 0, stream>>>(mask, bias_table, qkv_b, ws);
  winattn_main<<<4096, 512, 0, stream>>>(x, ws, proj_b, out);
}

// Round 8
// 497.600 us; speedup vs baseline: 1.1447x; 1.1447x over previous
//
#include <hip/hip_runtime.h>

typedef __attribute__((ext_vector_type(8))) short bf16x8;
typedef __attribute__((ext_vector_type(4))) float f32x4;

#define WS_QKV   0          // 384 KiB: qkv frags (48 rt * 8 ks * 1024B), q-rows prescaled
#define WS_PROJ  393216     // 128 KiB: proj frags (16 rt * 8 ks * 1024B)
#define WS_MB    524288     // 8 MiB: mb[w][h][64][64] f32 = (mask[w]+bias[h])*log2e
#define WS_QB    8912896    // 3 KiB: qkvb_s[768] (q part prescaled by scale*log2e)

#define QSCALE 0.17677669529663687f   // 1/sqrt(32)
#define LOG2E  1.4426950408889634f

__device__ __forceinline__ unsigned short f2bf(float f) {
  unsigned u = __builtin_bit_cast(unsigned, f);
  u += 0x7FFFu + ((u >> 16) & 1u);
  return (unsigned short)(u >> 16);
}

__device__ __forceinline__ unsigned long long pack4bf(f32x4 v) {
  unsigned long long r0 = f2bf(v[0]);
  unsigned long long r1 = f2bf(v[1]);
  unsigned long long r2 = f2bf(v[2]);
  unsigned long long r3 = f2bf(v[3]);
  return r0 | (r1 << 16) | (r2 << 32) | (r3 << 48);
}

// frag(rt,ks): lane l holds W[16*rt + (l&15)][32*ks + 8*(l>>4) + i], i=0..7 (bf16)
__global__ void prep_weights(const float* __restrict__ qkv_w,
                             const float* __restrict__ proj_w,
                             unsigned char* __restrict__ ws) {
  int g = blockIdx.x;   // 0..511
  int l = threadIdx.x;  // 0..63
  int lr = l & 15, lg = l >> 4;
  const float* src;
  float sc = 1.f;
  if (g < 384) {
    int rt = g >> 3, ks = g & 7;
    src = qkv_w + (size_t)(16 * rt + lr) * 256 + 32 * ks + 8 * lg;
    if (rt < 16) sc = QSCALE * LOG2E;  // fold scale and log2e into q rows
  } else {
    int p = g - 384;
    int rt = p >> 3, ks = p & 7;
    src = proj_w + (size_t)(16 * rt + lr) * 256 + 32 * ks + 8 * lg;
  }
  f32x4 a = *(const f32x4*)(src)*sc;
  f32x4 b = *(const f32x4*)(src + 4) * sc;
  unsigned long long* dst = (unsigned long long*)(ws + (size_t)g * 1024 + l * 16);
  dst[0] = pack4bf(a);
  dst[1] = pack4bf(b);
}

// mb[w][h][64][64] = (mask + rel-pos bias) * log2e, masked cols -> -1e30
__global__ void prep_aux(const float* __restrict__ mask,
                         const float* __restrict__ bias_table,
                         const float* __restrict__ qkv_b,
                         unsigned char* __restrict__ ws) {
  int bid = blockIdx.x, tid = threadIdx.x;
  if (bid < 512) {
    int w = bid >> 3, h = bid & 7;
    float* dst = (float*)(ws + WS_MB) + (size_t)bid * 4096;
    for (int it = 0; it < 16; ++it) {
      int idx = it * 256 + tid;
      int m = idx >> 6, j = idx & 63;
      float v;
      if (j >= 49) {
        v = -1e30f;
      } else {
        float bi = 0.f, mk = 0.f;
        if (m < 49) {
          int rm = m / 7, cm = m % 7, rj = j / 7, cj = j % 7;
          int rpi = (rm - rj + 6) * 13 + (cm - cj + 6);
          bi = bias_table[rpi * 8 + h];
          mk = mask[((size_t)w * 49 + m) * 49 + j];
        }
        v = (mk + bi) * LOG2E;
      }
      dst[idx] = v;
    }
  } else {  // qkv bias: q part prescaled
    float* dst = (float*)(ws + WS_QB);
    for (int i = tid; i < 768; i += 256)
      dst[i] = qkv_b[i] * (i < 256 ? QSCALE * LOG2E : 1.f);
  }
}

// One block = one window, 8 waves (512 thr), 2 passes of 4 heads.
// Wave wv: head-slot hs = wv>>1, m-half s = wv&1; pass p: head h = 4p + hs.
// LDS 77 KiB -> 2 blocks/CU (R7 proved 2x78848 co-residency).
// __launch_bounds__(512,2): CUDA minBlocks semantics -> 128-reg cap/wave.
// Register diet: Phase B streams ONE 16-ch weight tile at a time (af[8]=32
// regs, not af0+af1=64) so peak live ~110 total -> 4 waves/SIMD.
//  [0,32K)        xs: bf16 x[64][256], byte(r,c) = r*512 + ((2c)^((r&7)<<4));
//                 reused as ao[m][256ch] in the epilogue (same swizzle)
//  head-slot hs:  bufQ = 32768 + hs*9216  (q [64m][32d] stride 72; later
//                   vT [32d][64tok] stride 128, byte = d*128+((2t)^((d&7)<<4)))
//                 bufK = bufQ + 4608      (k [64m][32d] stride 72 — intact
//                   through the v-pass, kf read AFTER it: cuts reg pressure)
//  per wave:      bufP = 69632 + wv*1152  ([16m][32j] stride 72)
__global__ __launch_bounds__(512, 2)
void winattn_main(const float* __restrict__ x,
                  const unsigned char* __restrict__ ws,
                  const float* __restrict__ proj_b,
                  float* __restrict__ out) {
  __shared__ __align__(16) unsigned char lds[78848];
  const int tid = threadIdx.x;
  const int wv = tid >> 6, ln = tid & 63;
  const int lr = ln & 15, lg = ln >> 4;
  const int b = blockIdx.x;
  const int w = b & 63;
  const int hs = wv >> 1, s = wv & 1;
  const float* qbs = (const float*)(ws + WS_QB);
  unsigned char* bufQ = lds + 32768 + hs * 9216;  // q, then vT
  unsigned char* bufK = bufQ + 4608;
  unsigned char* bufP = lds + 69632 + wv * 1152;

  // ---- stage x -> xs (bf16, swizzled), rows >= 49 zeroed
  {
    const int r = tid >> 3;
    const int c0 = (tid & 7) * 4;
    const float* xrow = x + ((size_t)b * 49 + r) * 256;
    unsigned char* row = lds + r * 512;
    const int swz = (r & 7) << 4;
#pragma unroll
    for (int u = 0; u < 8; ++u) {
      int c = c0 + 32 * u;
      f32x4 v = {0.f, 0.f, 0.f, 0.f};
      if (r < 49) v = *(const f32x4*)(xrow + c);
      *(unsigned long long*)(row + ((2 * c) ^ swz)) = pack4bf(v);
    }
  }
  __syncthreads();

  unsigned long long aoPk[2][2][2];  // [pass][dt][i] packed bf16x4 (8 VGPRs)

#pragma unroll
  for (int p = 0; p < 2; ++p) {
    if (p) __syncthreads();  // bufQ/bufK reuse: pass1's vf/kf reads done
    const int h = 4 * p + hs;
    const float* mbp = (const float*)(ws + WS_MB) + ((size_t)(w * 8 + h)) * 4096;

    // ---- Phase B: q, k, v GEMMs; one 16-ch weight tile in flight at a time
    bf16x8 qf[2];
#pragma unroll
    for (int pp = 0; pp < 3; ++pp) {  // 0=q, 1=k, 2=v
      const int rtb = (pp == 0 ? 0 : (pp == 1 ? 16 : 32)) + 2 * h;
#pragma unroll
      for (int g2 = 0; g2 < 2; ++g2) {
        const int rt = rtb + g2;
        bf16x8 af[8];
#pragma unroll
        for (int ks = 0; ks < 8; ++ks)
          af[ks] = *(const bf16x8*)(ws + (size_t)(rt * 8 + ks) * 1024 + ln * 16);
        f32x4 cc;
        if (pp < 2) {
          cc = *(const f32x4*)(qbs + pp * 256 + 32 * h + 16 * g2 + 4 * lg);
        } else {
          float vb = qbs[512 + 32 * h + 16 * g2 + lr];
          cc = {vb, vb, vb, vb};
        }
#pragma unroll
        for (int ti = 0; ti < 2; ++ti) {
          const int t = 2 * s + ti;
          const int row = 16 * t + lr;
          const unsigned char* rp = lds + row * 512;
          const int swz = (row & 7) << 4;
          bf16x8 xfr[8];
#pragma unroll
          for (int ks = 0; ks < 8; ++ks)
            xfr[ks] = *(const bf16x8*)(rp + ((64 * ks + 16 * lg) ^ swz));
          f32x4 a = cc;
          if (pp < 2) {
            // D[ch][tok]: col = tok = 16t+lr, rows = ch = 16g2+4lg+r2
#pragma unroll
            for (int ks = 0; ks < 8; ++ks)
              a = __builtin_amdgcn_mfma_f32_16x16x32_bf16(af[ks], xfr[ks], a, 0, 0, 0);
            unsigned char* dst = (pp == 0 ? bufQ : bufK);
            *(unsigned long long*)(dst + row * 72 + 32 * g2 + 8 * lg) = pack4bf(a);
          } else {
            // D[tok][d]: col = d = 16g2+lr, rows = tok -> vT[d][tok] (q consumed)
#pragma unroll
            for (int ks = 0; ks < 8; ++ks)
              a = __builtin_amdgcn_mfma_f32_16x16x32_bf16(xfr[ks], af[ks], a, 0, 0, 0);
            const int tb = 32 * t + 8 * lg;
            *(unsigned long long*)(bufQ + (16 * g2 + lr) * 128 + (tb ^ ((lr & 7) << 4))) =
                pack4bf(a);
          }
        }
      }
      if (pp == 0) {
        // own half-rows only -> wave-private, no barrier needed
#pragma unroll
        for (int i = 0; i < 2; ++i)
          qf[i] = *(const bf16x8*)(bufQ + (lr + 32 * s + 16 * i) * 72 + 16 * lg);
      }
    }
    __syncthreads();  // k and vT fully staged (cross-wave within the pair)
    bf16x8 kf[4];
#pragma unroll
    for (int t = 0; t < 4; ++t)
      kf[t] = *(const bf16x8*)(bufK + (lr + 16 * t) * 72 + 16 * lg);

    // ---- Phase C: S^T = K Q^T (C-init = mb), exp2 softmax (no max-sub),
    //      online over j-halves; normalization deferred.
    float sm[2] = {0.f, 0.f};
    f32x4 oacc[2][2];
#pragma unroll
    for (int dt = 0; dt < 2; ++dt)
#pragma unroll
      for (int i = 0; i < 2; ++i) oacc[dt][i] = {0.f, 0.f, 0.f, 0.f};

#pragma unroll
    for (int jh = 0; jh < 2; ++jh) {
      f32x4 s2[2][2];
#pragma unroll
      for (int jt2 = 0; jt2 < 2; ++jt2) {
        const int jt = 2 * jh + jt2;
#pragma unroll
        for (int i = 0; i < 2; ++i) {
          const int m = lr + 32 * s + 16 * i;
          f32x4 mk = *(const f32x4*)(mbp + m * 64 + 16 * jt + 4 * lg);
          s2[jt2][i] = __builtin_amdgcn_mfma_f32_16x16x32_bf16(kf[jt], qf[i], mk, 0, 0, 0);
#pragma unroll
          for (int r2 = 0; r2 < 4; ++r2) {
            float e = __builtin_amdgcn_exp2f(s2[jt2][i][r2]);
            s2[jt2][i][r2] = e;
            sm[i] += e;
          }
        }
      }
      bf16x8 vf[2];
#pragma unroll
      for (int dt = 0; dt < 2; ++dt) {
        const int d = lr + 16 * dt;
        vf[dt] = *(const bf16x8*)(bufQ + d * 128 + ((64 * jh + 16 * lg) ^ ((d & 7) << 4)));
      }
#pragma unroll
      for (int i = 0; i < 2; ++i) {
#pragma unroll
        for (int jt2 = 0; jt2 < 2; ++jt2)
          *(unsigned long long*)(bufP + lr * 72 + 32 * jt2 + 8 * lg) = pack4bf(s2[jt2][i]);
        bf16x8 pf = *(const bf16x8*)(bufP + lr * 72 + 16 * lg);
#pragma unroll
        for (int dt = 0; dt < 2; ++dt)
          oacc[dt][i] = __builtin_amdgcn_mfma_f32_16x16x32_bf16(vf[dt], pf, oacc[dt][i], 0, 0, 0);
      }
    }
#pragma unroll
    for (int i = 0; i < 2; ++i) {
      float t = sm[i];
      t += __shfl_xor(t, 16);
      t += __shfl_xor(t, 32);
      float inv = 1.f / t;
#pragma unroll
      for (int dt = 0; dt < 2; ++dt) aoPk[p][dt][i] = pack4bf(oacc[dt][i] * inv);
    }
  }

  __syncthreads();  // all attention done; xs reads (pass-2 xfr) done

  // ao[m][256] into xs region: head h owns bytes [64h, 64h+64) per row
#pragma unroll
  for (int p = 0; p < 2; ++p) {
    const int h = 4 * p + hs;
#pragma unroll
    for (int dt = 0; dt < 2; ++dt)
#pragma unroll
      for (int i = 0; i < 2; ++i) {
        const int m = lr + 32 * s + 16 * i;
        *(unsigned long long*)(lds + m * 512 +
                               ((64 * h + 32 * dt + 8 * lg) ^ ((m & 7) << 4))) =
            aoPk[p][dt][i];
      }
  }
  __syncthreads();

  // ---- Phase D: proj^T[o][m] = sum_c Wp[o][c] * ao[m][c]
  const unsigned char* wsP = ws + WS_PROJ;
#pragma unroll
  for (int tt = 0; tt < 4; ++tt) {
    const int m = lr + 16 * tt;
    bf16x8 aof[8];
#pragma unroll
    for (int ks = 0; ks < 8; ++ks)
      aof[ks] = *(const bf16x8*)(lds + m * 512 + ((64 * ks + 16 * lg) ^ ((m & 7) << 4)));
#pragma unroll
    for (int i2 = 0; i2 < 2; ++i2) {
      const int mt = 2 * wv + i2;
      bf16x8 af[8];
#pragma unroll
      for (int ks = 0; ks < 8; ++ks)
        af[ks] = *(const bf16x8*)(wsP + (size_t)(mt * 8 + ks) * 1024 + ln * 16);
      f32x4 acc = {0.f, 0.f, 0.f, 0.f};
#pragma unroll
      for (int ks = 0; ks < 8; ++ks)
        acc = __builtin_amdgcn_mfma_f32_16x16x32_bf16(af[ks], aof[ks], acc, 0, 0, 0);
      if (m < 49) {
        f32x4 pb = *(const f32x4*)(proj_b + 16 * mt + 4 * lg);
        acc += pb;
        *(f32x4*)(out + ((size_t)b * 49 + m) * 256 + 16 * mt + 4 * lg) = acc;
      }
    }
  }
}

extern "C" void kernel_launch(void* const* d_in, const int* in_sizes, int n_in,
                              void* d_out, int out_size, void* d_ws, size_t ws_size,
                              hipStream_t stream) {
  const float* x = (const float*)d_in[0];
  const float* mask = (const float*)d_in[1];
  const float* qkv_w = (const float*)d_in[2];
  const float* qkv_b = (const float*)d_in[3];
  const float* proj_w = (const float*)d_in[4];
  const float* proj_b = (const float*)d_in[5];
  const float* bias_table = (const float*)d_in[6];
  unsigned char* ws = (unsigned char*)d_ws;
  float* out = (float*)d_out;

  prep_weights<<<512, 64, 0, stream>>>(qkv_w, proj_w, ws);
  prep_aux<<<513, 256, 0, stream>>>(mask, bias_table, qkv_b, ws);
  winattn_main<<<4096, 512, 0, stream>>>(x, ws, proj_b, out);
}

// Round 9
// 485.884 us; speedup vs baseline: 1.1723x; 1.0241x over previous
//
#include <hip/hip_runtime.h>

typedef __attribute__((ext_vector_type(8))) short bf16x8;
typedef __attribute__((ext_vector_type(4))) float f32x4;

#define WS_QKV   0          // 384 KiB: qkv frags (48 rt * 8 ks * 1024B), q-rows prescaled
#define WS_PROJ  393216     // 128 KiB: proj frags (16 rt * 8 ks * 1024B)
#define WS_MB    524288     // 8 MiB: mb[w][h][64][64] f32 = (mask[w]+bias[h])*log2e
#define WS_QB    8912896    // 3 KiB: qkvb_s[768] (q part prescaled by scale*log2e)

#define QSCALE 0.17677669529663687f   // 1/sqrt(32)
#define LOG2E  1.4426950408889634f

__device__ __forceinline__ unsigned short f2bf(float f) {
  unsigned u = __builtin_bit_cast(unsigned, f);
  u += 0x7FFFu + ((u >> 16) & 1u);
  return (unsigned short)(u >> 16);
}

__device__ __forceinline__ unsigned long long pack4bf(f32x4 v) {
  unsigned long long r0 = f2bf(v[0]);
  unsigned long long r1 = f2bf(v[1]);
  unsigned long long r2 = f2bf(v[2]);
  unsigned long long r3 = f2bf(v[3]);
  return r0 | (r1 << 16) | (r2 << 32) | (r3 << 48);
}

// frag(rt,ks): lane l holds W[16*rt + (l&15)][32*ks + 8*(l>>4) + i], i=0..7 (bf16)
__global__ void prep_weights(const float* __restrict__ qkv_w,
                             const float* __restrict__ proj_w,
                             unsigned char* __restrict__ ws) {
  int g = blockIdx.x;   // 0..511
  int l = threadIdx.x;  // 0..63
  int lr = l & 15, lg = l >> 4;
  const float* src;
  float sc = 1.f;
  if (g < 384) {
    int rt = g >> 3, ks = g & 7;
    src = qkv_w + (size_t)(16 * rt + lr) * 256 + 32 * ks + 8 * lg;
    if (rt < 16) sc = QSCALE * LOG2E;  // fold scale and log2e into q rows
  } else {
    int p = g - 384;
    int rt = p >> 3, ks = p & 7;
    src = proj_w + (size_t)(16 * rt + lr) * 256 + 32 * ks + 8 * lg;
  }
  f32x4 a = *(const f32x4*)(src)*sc;
  f32x4 b = *(const f32x4*)(src + 4) * sc;
  unsigned long long* dst = (unsigned long long*)(ws + (size_t)g * 1024 + l * 16);
  dst[0] = pack4bf(a);
  dst[1] = pack4bf(b);
}

// mb[w][h][64][64] = (mask + rel-pos bias) * log2e, masked cols -> -1e30
__global__ void prep_aux(const float* __restrict__ mask,
                         const float* __restrict__ bias_table,
                         const float* __restrict__ qkv_b,
                         unsigned char* __restrict__ ws) {
  int bid = blockIdx.x, tid = threadIdx.x;
  if (bid < 512) {
    int w = bid >> 3, h = bid & 7;
    float* dst = (float*)(ws + WS_MB) + (size_t)bid * 4096;
    for (int it = 0; it < 16; ++it) {
      int idx = it * 256 + tid;
      int m = idx >> 6, j = idx & 63;
      float v;
      if (j >= 49) {
        v = -1e30f;
      } else {
        float bi = 0.f, mk = 0.f;
        if (m < 49) {
          int rm = m / 7, cm = m % 7, rj = j / 7, cj = j % 7;
          int rpi = (rm - rj + 6) * 13 + (cm - cj + 6);
          bi = bias_table[rpi * 8 + h];
          mk = mask[((size_t)w * 49 + m) * 49 + j];
        }
        v = (mk + bi) * LOG2E;
      }
      dst[idx] = v;
    }
  } else {  // qkv bias: q part prescaled
    float* dst = (float*)(ws + WS_QB);
    for (int i = tid; i < 768; i += 256)
      dst[i] = qkv_b[i] * (i < 256 ? QSCALE * LOG2E : 1.f);
  }
}

// One block = one window, 8 waves (512 thr), 2 passes of 4 heads.
// Wave wv: head-slot hs = wv>>1, m-half s = wv&1; pass p: head h = 4p + hs.
// LDS 77 KiB -> 2 blocks/CU. Register diet targets arch+acc <= 128/wave
// (4 waves/SIMD): Phase B holds xfr4[4] not xfr[8]; Phase C computes each
// QK fragment transiently (mfma->exp2->LDS write) instead of batching s2.
//  [0,32K)        xs: bf16 x[64][256], byte(r,c) = r*512 + ((2c)^((r&7)<<4));
//                 reused as ao[m][256ch] in the epilogue (same swizzle)
//  head-slot hs:  bufQ = 32768 + hs*9216  (q [64m][32d] stride 72; later
//                   vT [32d][64tok] stride 128, byte = d*128+((2t)^((d&7)<<4)))
//                 bufK = bufQ + 4608      (k [64m][32d] stride 72)
//  per wave:      bufP = 69632 + wv*1152  ([16m][32j] stride 72)
__global__ __launch_bounds__(512, 2)
void winattn_main(const float* __restrict__ x,
                  const unsigned char* __restrict__ ws,
                  const float* __restrict__ proj_b,
                  float* __restrict__ out) {
  __shared__ __align__(16) unsigned char lds[78848];
  const int tid = threadIdx.x;
  const int wv = tid >> 6, ln = tid & 63;
  const int lr = ln & 15, lg = ln >> 4;
  const int b = blockIdx.x;
  const int w = b & 63;
  const int hs = wv >> 1, s = wv & 1;
  const float* qbs = (const float*)(ws + WS_QB);
  unsigned char* bufQ = lds + 32768 + hs * 9216;  // q, then vT
  unsigned char* bufK = bufQ + 4608;
  unsigned char* bufP = lds + 69632 + wv * 1152;

  // ---- stage x -> xs (bf16, swizzled), rows >= 49 zeroed
  {
    const int r = tid >> 3;
    const int c0 = (tid & 7) * 4;
    const float* xrow = x + ((size_t)b * 49 + r) * 256;
    unsigned char* row = lds + r * 512;
    const int swz = (r & 7) << 4;
#pragma unroll
    for (int u = 0; u < 8; ++u) {
      int c = c0 + 32 * u;
      f32x4 v = {0.f, 0.f, 0.f, 0.f};
      if (r < 49) v = *(const f32x4*)(xrow + c);
      *(unsigned long long*)(row + ((2 * c) ^ swz)) = pack4bf(v);
    }
  }
  __syncthreads();

  unsigned long long aoPk[2][2][2];  // [pass][dt][i] packed bf16x4 (8 VGPRs)

#pragma unroll
  for (int p = 0; p < 2; ++p) {
    if (p) __syncthreads();  // bufQ/bufK reuse: pass1's vf/kf reads done
    const int h = 4 * p + hs;
    const float* mbp = (const float*)(ws + WS_MB) + ((size_t)(w * 8 + h)) * 4096;

    // ---- Phase B: q, k, v GEMMs; af[8] held, xfr streamed 4-at-a-time
    bf16x8 qf[2];
#pragma unroll
    for (int pp = 0; pp < 3; ++pp) {  // 0=q, 1=k, 2=v
      const int rtb = (pp == 0 ? 0 : (pp == 1 ? 16 : 32)) + 2 * h;
#pragma unroll
      for (int g2 = 0; g2 < 2; ++g2) {
        const int rt = rtb + g2;
        bf16x8 af[8];
#pragma unroll
        for (int ks = 0; ks < 8; ++ks)
          af[ks] = *(const bf16x8*)(ws + (size_t)(rt * 8 + ks) * 1024 + ln * 16);
        f32x4 cc;
        if (pp < 2) {
          cc = *(const f32x4*)(qbs + pp * 256 + 32 * h + 16 * g2 + 4 * lg);
        } else {
          float vb = qbs[512 + 32 * h + 16 * g2 + lr];
          cc = {vb, vb, vb, vb};
        }
#pragma unroll
        for (int ti = 0; ti < 2; ++ti) {
          const int t = 2 * s + ti;
          const int row = 16 * t + lr;
          const unsigned char* rp = lds + row * 512;
          const int swz = (row & 7) << 4;
          f32x4 a = cc;
          if (pp < 2) {
            // D[ch][tok]: col = tok = 16t+lr, rows = ch = 16g2+4lg+r2
#pragma unroll
            for (int hf = 0; hf < 2; ++hf) {
              bf16x8 xfr4[4];
#pragma unroll
              for (int kk = 0; kk < 4; ++kk)
                xfr4[kk] = *(const bf16x8*)(rp + ((64 * (4 * hf + kk) + 16 * lg) ^ swz));
#pragma unroll
              for (int kk = 0; kk < 4; ++kk)
                a = __builtin_amdgcn_mfma_f32_16x16x32_bf16(af[4 * hf + kk], xfr4[kk], a, 0, 0, 0);
            }
            unsigned char* dst = (pp == 0 ? bufQ : bufK);
            *(unsigned long long*)(dst + row * 72 + 32 * g2 + 8 * lg) = pack4bf(a);
          } else {
            // D[tok][d]: col = d = 16g2+lr, rows = tok -> vT[d][tok] (q consumed)
#pragma unroll
            for (int hf = 0; hf < 2; ++hf) {
              bf16x8 xfr4[4];
#pragma unroll
              for (int kk = 0; kk < 4; ++kk)
                xfr4[kk] = *(const bf16x8*)(rp + ((64 * (4 * hf + kk) + 16 * lg) ^ swz));
#pragma unroll
              for (int kk = 0; kk < 4; ++kk)
                a = __builtin_amdgcn_mfma_f32_16x16x32_bf16(xfr4[kk], af[4 * hf + kk], a, 0, 0, 0);
            }
            const int tb = 32 * t + 8 * lg;
            *(unsigned long long*)(bufQ + (16 * g2 + lr) * 128 + (tb ^ ((lr & 7) << 4))) =
                pack4bf(a);
          }
        }
      }
      if (pp == 0) {
        // own half-rows only -> wave-private, no barrier needed
#pragma unroll
        for (int i = 0; i < 2; ++i)
          qf[i] = *(const bf16x8*)(bufQ + (lr + 32 * s + 16 * i) * 72 + 16 * lg);
      }
    }
    __syncthreads();  // k and vT fully staged (cross-wave within the pair)
    bf16x8 kf[4];
#pragma unroll
    for (int t = 0; t < 4; ++t)
      kf[t] = *(const bf16x8*)(bufK + (lr + 16 * t) * 72 + 16 * lg);

    // ---- Phase C: per-i transient QK fragments -> bufP -> PV
    float sm[2] = {0.f, 0.f};
    f32x4 oacc[2][2];
#pragma unroll
    for (int dt = 0; dt < 2; ++dt)
#pragma unroll
      for (int i = 0; i < 2; ++i) oacc[dt][i] = {0.f, 0.f, 0.f, 0.f};

#pragma unroll
    for (int jh = 0; jh < 2; ++jh) {
      bf16x8 vf[2];
#pragma unroll
      for (int dt = 0; dt < 2; ++dt) {
        const int d = lr + 16 * dt;
        vf[dt] = *(const bf16x8*)(bufQ + d * 128 + ((64 * jh + 16 * lg) ^ ((d & 7) << 4)));
      }
#pragma unroll
      for (int i = 0; i < 2; ++i) {
        const int m = lr + 32 * s + 16 * i;
#pragma unroll
        for (int jt2 = 0; jt2 < 2; ++jt2) {
          const int jt = 2 * jh + jt2;
          f32x4 mk = *(const f32x4*)(mbp + m * 64 + 16 * jt + 4 * lg);
          f32x4 sv = __builtin_amdgcn_mfma_f32_16x16x32_bf16(kf[jt], qf[i], mk, 0, 0, 0);
#pragma unroll
          for (int r2 = 0; r2 < 4; ++r2) {
            float e = __builtin_amdgcn_exp2f(sv[r2]);
            sv[r2] = e;
            sm[i] += e;
          }
          *(unsigned long long*)(bufP + lr * 72 + 32 * jt2 + 8 * lg) = pack4bf(sv);
        }
        bf16x8 pf = *(const bf16x8*)(bufP + lr * 72 + 16 * lg);
#pragma unroll
        for (int dt = 0; dt < 2; ++dt)
          oacc[dt][i] = __builtin_amdgcn_mfma_f32_16x16x32_bf16(vf[dt], pf, oacc[dt][i], 0, 0, 0);
      }
    }
#pragma unroll
    for (int i = 0; i < 2; ++i) {
      float t = sm[i];
      t += __shfl_xor(t, 16);
      t += __shfl_xor(t, 32);
      float inv = 1.f / t;
#pragma unroll
      for (int dt = 0; dt < 2; ++dt) aoPk[p][dt][i] = pack4bf(oacc[dt][i] * inv);
    }
  }

  __syncthreads();  // all attention done; xs reads (pass-2 xfr) done

  // ao[m][256] into xs region: head h owns bytes [64h, 64h+64) per row
#pragma unroll
  for (int p = 0; p < 2; ++p) {
    const int h = 4 * p + hs;
#pragma unroll
    for (int dt = 0; dt < 2; ++dt)
#pragma unroll
      for (int i = 0; i < 2; ++i) {
        const int m = lr + 32 * s + 16 * i;
        *(unsigned long long*)(lds + m * 512 +
                               ((64 * h + 32 * dt + 8 * lg) ^ ((m & 7) << 4))) =
            aoPk[p][dt][i];
      }
  }
  __syncthreads();

  // ---- Phase D: proj^T[o][m] = sum_c Wp[o][c] * ao[m][c]
  const unsigned char* wsP = ws + WS_PROJ;
#pragma unroll
  for (int tt = 0; tt < 4; ++tt) {
    const int m = lr + 16 * tt;
    bf16x8 aof[8];
#pragma unroll
    for (int ks = 0; ks < 8; ++ks)
      aof[ks] = *(const bf16x8*)(lds + m * 512 + ((64 * ks + 16 * lg) ^ ((m & 7) << 4)));
#pragma unroll
    for (int i2 = 0; i2 < 2; ++i2) {
      const int mt = 2 * wv + i2;
      bf16x8 af[8];
#pragma unroll
      for (int ks = 0; ks < 8; ++ks)
        af[ks] = *(const bf16x8*)(wsP + (size_t)(mt * 8 + ks) * 1024 + ln * 16);
      f32x4 acc = {0.f, 0.f, 0.f, 0.f};
#pragma unroll
      for (int ks = 0; ks < 8; ++ks)
        acc = __builtin_amdgcn_mfma_f32_16x16x32_bf16(af[ks], aof[ks], acc, 0, 0, 0);
      if (m < 49) {
        f32x4 pb = *(const f32x4*)(proj_b + 16 * mt + 4 * lg);
        acc += pb;
        *(f32x4*)(out + ((size_t)b * 49 + m) * 256 + 16 * mt + 4 * lg) = acc;
      }
    }
  }
}

extern "C" void kernel_launch(void* const* d_in, const int* in_sizes, int n_in,
                              void* d_out, int out_size, void* d_ws, size_t ws_size,
                              hipStream_t stream) {
  const float* x = (const float*)d_in[0];
  const float* mask = (const float*)d_in[1];
  const float* qkv_w = (const float*)d_in[2];
  const float* qkv_b = (const float*)d_in[3];
  const float* proj_w = (const float*)d_in[4];
  const float* proj_b = (const float*)d_in[5];
  const float* bias_table = (const float*)d_in[6];
  unsigned char* ws = (unsigned char*)d_ws;
  float* out = (float*)d_out;

  prep_weights<<<512, 64, 0, stream>>>(qkv_w, proj_w, ws);
  prep_aux<<<513, 256, 0, stream>>>(mask, bias_table, qkv_b, ws);
  winattn_main<<<4096, 512, 0, stream>>>(x, ws, proj_b, out);
}

// Round 10
// 334.508 us; speedup vs baseline: 1.7028x; 1.4525x over previous
//
#include <hip/hip_runtime.h>

typedef __attribute__((ext_vector_type(8))) short bf16x8;
typedef __attribute__((ext_vector_type(4))) float f32x4;
typedef __attribute__((ext_vector_type(2))) unsigned long long u64x2;

#define WS_QKV   0          // 384 KiB: qkv frags (48 rt * 8 ks * 1024B), q-rows prescaled
#define WS_PROJ  393216     // 128 KiB: proj frags (16 rt * 8 ks * 1024B)
#define WS_MB    524288     // 8 MiB: mb[w][h][64][64] f32 = (mask[w]+bias[h])*log2e
#define WS_QB    8912896    // 3 KiB: qkvb_s[768] (q part prescaled by scale*log2e)

#define QSCALE 0.17677669529663687f   // 1/sqrt(32)
#define LOG2E  1.4426950408889634f

__device__ __forceinline__ unsigned short f2bf(float f) {
  unsigned u = __builtin_bit_cast(unsigned, f);
  u += 0x7FFFu + ((u >> 16) & 1u);
  return (unsigned short)(u >> 16);
}

__device__ __forceinline__ unsigned long long pack4bf(f32x4 v) {
  unsigned long long r0 = f2bf(v[0]);
  unsigned long long r1 = f2bf(v[1]);
  unsigned long long r2 = f2bf(v[2]);
  unsigned long long r3 = f2bf(v[3]);
  return r0 | (r1 << 16) | (r2 << 32) | (r3 << 48);
}

// frag(rt,ks): lane l holds W[16*rt + (l&15)][32*ks + 8*(l>>4) + i], i=0..7 (bf16)
__global__ void prep_weights(const float* __restrict__ qkv_w,
                             const float* __restrict__ proj_w,
                             unsigned char* __restrict__ ws) {
  int g = blockIdx.x;   // 0..511
  int l = threadIdx.x;  // 0..63
  int lr = l & 15, lg = l >> 4;
  const float* src;
  float sc = 1.f;
  if (g < 384) {
    int rt = g >> 3, ks = g & 7;
    src = qkv_w + (size_t)(16 * rt + lr) * 256 + 32 * ks + 8 * lg;
    if (rt < 16) sc = QSCALE * LOG2E;  // fold scale and log2e into q rows
  } else {
    int p = g - 384;
    int rt = p >> 3, ks = p & 7;
    src = proj_w + (size_t)(16 * rt + lr) * 256 + 32 * ks + 8 * lg;
  }
  f32x4 a = *(const f32x4*)(src)*sc;
  f32x4 b = *(const f32x4*)(src + 4) * sc;
  unsigned long long* dst = (unsigned long long*)(ws + (size_t)g * 1024 + l * 16);
  dst[0] = pack4bf(a);
  dst[1] = pack4bf(b);
}

// mb[w][h][64][64] = (mask + rel-pos bias) * log2e, masked cols -> -1e30
__global__ void prep_aux(const float* __restrict__ mask,
                         const float* __restrict__ bias_table,
                         const float* __restrict__ qkv_b,
                         unsigned char* __restrict__ ws) {
  int bid = blockIdx.x, tid = threadIdx.x;
  if (bid < 512) {
    int w = bid >> 3, h = bid & 7;
    float* dst = (float*)(ws + WS_MB) + (size_t)bid * 4096;
    for (int it = 0; it < 16; ++it) {
      int idx = it * 256 + tid;
      int m = idx >> 6, j = idx & 63;
      float v;
      if (j >= 49) {
        v = -1e30f;
      } else {
        float bi = 0.f, mk = 0.f;
        if (m < 49) {
          int rm = m / 7, cm = m % 7, rj = j / 7, cj = j % 7;
          int rpi = (rm - rj + 6) * 13 + (cm - cj + 6);
          bi = bias_table[rpi * 8 + h];
          mk = mask[((size_t)w * 49 + m) * 49 + j];
        }
        v = (mk + bi) * LOG2E;
      }
      dst[idx] = v;
    }
  } else {  // qkv bias: q part prescaled
    float* dst = (float*)(ws + WS_QB);
    for (int i = tid; i < 768; i += 256)
      dst[i] = qkv_b[i] * (i < 256 ? QSCALE * LOG2E : 1.f);
  }
}

// One block = one window, 4 waves (256 thr), 4 passes of 2 heads.
// Wave wv: head-slot hs = wv>>1, m-half s = wv&1; pass p: head h = 2p + hs.
// x fragments live in REGISTERS (xf[2][8], 64 VGPR) for the whole kernel:
// Phase B has ZERO LDS reads. LDS 50 KiB -> up to 3 blocks/CU.
//  [0,32K)        aoR: ao[m][256ch] bf16, byte = m*512 + (2c ^ ((m&7)<<4))
//  head-slot hs:  bufQ = 32768 + hs*9216 (q [64m][32d] stride 72; then vT
//                   [32d][64tok] stride 128, byte = d*128+((2t)^((d&7)<<4)))
//                 bufK = bufQ + 4608     (k [64m][32d] stride 72)
//  per wave:      bufP = bufK + s*1152   ([16m][32j] stride 72, after kf read)
__global__ __launch_bounds__(256, 2)
void winattn_main(const float* __restrict__ x,
                  const unsigned char* __restrict__ ws,
                  const float* __restrict__ proj_b,
                  float* __restrict__ out) {
  __shared__ __align__(16) unsigned char lds[51200];
  const int tid = threadIdx.x;
  const int wv = tid >> 6, ln = tid & 63;
  const int lr = ln & 15, lg = ln >> 4;
  const int b = blockIdx.x;
  const int w = b & 63;
  const int hs = wv >> 1, s = wv & 1;
  const float* qbs = (const float*)(ws + WS_QB);
  unsigned char* aoR = lds;
  unsigned char* bufQ = lds + 32768 + hs * 9216;  // q, then vT
  unsigned char* bufK = bufQ + 4608;
  unsigned char* bufP = bufK + s * 1152;

  // ---- x fragments -> registers (held for entire kernel); rows >= 49 zero
  bf16x8 xf[2][8];
#pragma unroll
  for (int ti = 0; ti < 2; ++ti) {
    const int row = 16 * (2 * s + ti) + lr;
    const float* xr = x + ((size_t)b * 49 + row) * 256 + 8 * lg;
    const bool val = (row < 49);
#pragma unroll
    for (int ks = 0; ks < 8; ++ks) {
      f32x4 va = {0.f, 0.f, 0.f, 0.f}, vb = {0.f, 0.f, 0.f, 0.f};
      if (val) {
        va = *(const f32x4*)(xr + 32 * ks);
        vb = *(const f32x4*)(xr + 32 * ks + 4);
      }
      u64x2 t2 = {pack4bf(va), pack4bf(vb)};
      xf[ti][ks] = __builtin_bit_cast(bf16x8, t2);
    }
  }

  for (int p = 0; p < 4; ++p) {
    if (p) __syncthreads();  // prior pass's vf/pf reads done before restage
    const int h = 2 * p + hs;
    const float* mbp = (const float*)(ws + WS_MB) + ((size_t)(w * 8 + h)) * 4096;

    // ---- Phase B: q,k GEMMs (no LDS reads; af from L2-hot ws)
#pragma unroll
    for (int pp = 0; pp < 2; ++pp) {
      unsigned char* dst = (pp == 0 ? bufQ : bufK);
#pragma unroll
      for (int g2 = 0; g2 < 2; ++g2) {
        const int rt = pp * 16 + 2 * h + g2;
        bf16x8 af[8];
#pragma unroll
        for (int ks = 0; ks < 8; ++ks)
          af[ks] = *(const bf16x8*)(ws + (size_t)(rt * 8 + ks) * 1024 + ln * 16);
        f32x4 cc = *(const f32x4*)(qbs + pp * 256 + 32 * h + 16 * g2 + 4 * lg);
#pragma unroll
        for (int ti = 0; ti < 2; ++ti) {
          const int row = 16 * (2 * s + ti) + lr;
          f32x4 a = cc;
#pragma unroll
          for (int ks = 0; ks < 8; ++ks)
            a = __builtin_amdgcn_mfma_f32_16x16x32_bf16(af[ks], xf[ti][ks], a, 0, 0, 0);
          *(unsigned long long*)(dst + row * 72 + 32 * g2 + 8 * lg) = pack4bf(a);
        }
      }
    }
    bf16x8 qf[2];
#pragma unroll
    for (int i = 0; i < 2; ++i)  // own rows -> no barrier needed
      qf[i] = *(const bf16x8*)(bufQ + (lr + 32 * s + 16 * i) * 72 + 16 * lg);
    __syncthreads();  // partner's qf read done before vT clobbers q region

    // v GEMM -> vT into bufQ (q consumed)
#pragma unroll
    for (int g2 = 0; g2 < 2; ++g2) {
      const int rt = 32 + 2 * h + g2;
      bf16x8 af[8];
#pragma unroll
      for (int ks = 0; ks < 8; ++ks)
        af[ks] = *(const bf16x8*)(ws + (size_t)(rt * 8 + ks) * 1024 + ln * 16);
      const float vb = qbs[512 + 32 * h + 16 * g2 + lr];
      f32x4 cc = {vb, vb, vb, vb};
#pragma unroll
      for (int ti = 0; ti < 2; ++ti) {
        const int t = 2 * s + ti;
        f32x4 a = cc;
#pragma unroll
        for (int ks = 0; ks < 8; ++ks)
          a = __builtin_amdgcn_mfma_f32_16x16x32_bf16(xf[ti][ks], af[ks], a, 0, 0, 0);
        const int d = 16 * g2 + lr;
        *(unsigned long long*)(bufQ + d * 128 + ((32 * t + 8 * lg) ^ ((d & 7) << 4))) =
            pack4bf(a);
      }
    }
    __syncthreads();  // k + vT staged pair-wide
    bf16x8 kf[4];
#pragma unroll
    for (int t = 0; t < 4; ++t)
      kf[t] = *(const bf16x8*)(bufK + (lr + 16 * t) * 72 + 16 * lg);
    __syncthreads();  // both waves' kf consumed before bufP (in bufK) writes

    // ---- Phase C: S^T = K Q^T (C-init = mb), exp2 softmax, PV
    float sm[2] = {0.f, 0.f};
    f32x4 oacc[2][2];
#pragma unroll
    for (int dt = 0; dt < 2; ++dt)
#pragma unroll
      for (int i = 0; i < 2; ++i) oacc[dt][i] = {0.f, 0.f, 0.f, 0.f};
#pragma unroll
    for (int jh = 0; jh < 2; ++jh) {
      bf16x8 vf[2];
#pragma unroll
      for (int dt = 0; dt < 2; ++dt) {
        const int d = lr + 16 * dt;
        vf[dt] = *(const bf16x8*)(bufQ + d * 128 + ((64 * jh + 16 * lg) ^ ((d & 7) << 4)));
      }
#pragma unroll
      for (int i = 0; i < 2; ++i) {
        const int m = lr + 32 * s + 16 * i;
#pragma unroll
        for (int jt2 = 0; jt2 < 2; ++jt2) {
          const int jt = 2 * jh + jt2;
          f32x4 mk = *(const f32x4*)(mbp + m * 64 + 16 * jt + 4 * lg);
          f32x4 sv = __builtin_amdgcn_mfma_f32_16x16x32_bf16(kf[jt], qf[i], mk, 0, 0, 0);
#pragma unroll
          for (int r2 = 0; r2 < 4; ++r2) {
            float e = __builtin_amdgcn_exp2f(sv[r2]);
            sv[r2] = e;
            sm[i] += e;
          }
          *(unsigned long long*)(bufP + lr * 72 + 32 * jt2 + 8 * lg) = pack4bf(sv);
        }
        bf16x8 pf = *(const bf16x8*)(bufP + lr * 72 + 16 * lg);
#pragma unroll
        for (int dt = 0; dt < 2; ++dt)
          oacc[dt][i] = __builtin_amdgcn_mfma_f32_16x16x32_bf16(vf[dt], pf, oacc[dt][i], 0, 0, 0);
      }
    }
    // normalize + write ao for this head into aoR
#pragma unroll
    for (int i = 0; i < 2; ++i) {
      float t = sm[i];
      t += __shfl_xor(t, 16);
      t += __shfl_xor(t, 32);
      const float inv = 1.f / t;
      const int m = lr + 32 * s + 16 * i;
#pragma unroll
      for (int dt = 0; dt < 2; ++dt)
        *(unsigned long long*)(aoR + m * 512 +
                               ((64 * h + 32 * dt + 8 * lg) ^ ((m & 7) << 4))) =
            pack4bf(oacc[dt][i] * inv);
    }
  }
  __syncthreads();  // all heads' ao staged

  // ---- Phase D: proj^T[o][m] = sum_c Wp[o][c] * ao[m][c]
  const unsigned char* wsP = ws + WS_PROJ;
#pragma unroll
  for (int tt = 0; tt < 4; ++tt) {
    const int m = lr + 16 * tt;
    bf16x8 aof[8];
#pragma unroll
    for (int ks = 0; ks < 8; ++ks)
      aof[ks] = *(const bf16x8*)(aoR + m * 512 + ((64 * ks + 16 * lg) ^ ((m & 7) << 4)));
#pragma unroll
    for (int i2 = 0; i2 < 4; ++i2) {
      const int mt = 4 * wv + i2;
      bf16x8 af[8];
#pragma unroll
      for (int ks = 0; ks < 8; ++ks)
        af[ks] = *(const bf16x8*)(wsP + (size_t)(mt * 8 + ks) * 1024 + ln * 16);
      f32x4 acc = {0.f, 0.f, 0.f, 0.f};
#pragma unroll
      for (int ks = 0; ks < 8; ++ks)
        acc = __builtin_amdgcn_mfma_f32_16x16x32_bf16(af[ks], aof[ks], acc, 0, 0, 0);
      if (m < 49) {
        f32x4 pb = *(const f32x4*)(proj_b + 16 * mt + 4 * lg);
        acc += pb;
        *(f32x4*)(out + ((size_t)b * 49 + m) * 256 + 16 * mt + 4 * lg) = acc;
      }
    }
  }
}

extern "C" void kernel_launch(void* const* d_in, const int* in_sizes, int n_in,
                              void* d_out, int out_size, void* d_ws, size_t ws_size,
                              hipStream_t stream) {
  const float* x = (const float*)d_in[0];
  const float* mask = (const float*)d_in[1];
  const float* qkv_w = (const float*)d_in[2];
  const float* qkv_b = (const float*)d_in[3];
  const float* proj_w = (const float*)d_in[4];
  const float* proj_b = (const float*)d_in[5];
  const float* bias_table = (const float*)d_in[6];
  unsigned char* ws = (unsigned char*)d_ws;
  float* out = (float*)d_out;

  prep_weights<<<512, 64, 0, stream>>>(qkv_w, proj_w, ws);
  prep_aux<<<513, 256, 0, stream>>>(mask, bias_table, qkv_b, ws);
  winattn_main<<<4096, 256, 0, stream>>>(x, ws, proj_b, out);
}

// Round 12
// 316.263 us; speedup vs baseline: 1.8010x; 1.0577x over previous
//
#include <hip/hip_runtime.h>

typedef __attribute__((ext_vector_type(8))) short bf16x8;
typedef __attribute__((ext_vector_type(4))) float f32x4;
typedef __attribute__((ext_vector_type(2))) unsigned long long u64x2;

#define WS_QKV   0          // 384 KiB: qkv frags (48 rt * 8 ks * 1024B), q-rows prescaled
#define WS_PROJ  393216     // 128 KiB: proj frags (16 rt * 8 ks * 1024B)
#define WS_MB    524288     // 8 MiB: mb[w][h][64][64] f32 = (mask[w]+bias[h])*log2e
#define WS_QB    8912896    // 3 KiB: qkvb_s[768] (q part prescaled by scale*log2e)

#define QSCALE 0.17677669529663687f   // 1/sqrt(32)
#define LOG2E  1.4426950408889634f

// RNE f32->bf16 bit-twiddle (proven R0-R10; guide m240: don't hand-write cvt_pk asm)
__device__ __forceinline__ unsigned short f2bf(float f) {
  unsigned u = __builtin_bit_cast(unsigned, f);
  u += 0x7FFFu + ((u >> 16) & 1u);
  return (unsigned short)(u >> 16);
}

__device__ __forceinline__ unsigned long long pack4bf(f32x4 v) {
  unsigned long long r0 = f2bf(v[0]);
  unsigned long long r1 = f2bf(v[1]);
  unsigned long long r2 = f2bf(v[2]);
  unsigned long long r3 = f2bf(v[3]);
  return r0 | (r1 << 16) | (r2 << 32) | (r3 << 48);
}

// frag(rt,ks): lane l holds W[16*rt + (l&15)][32*ks + 8*(l>>4) + i], i=0..7 (bf16)
__global__ void prep_weights(const float* __restrict__ qkv_w,
                             const float* __restrict__ proj_w,
                             unsigned char* __restrict__ ws) {
  int g = blockIdx.x;   // 0..511
  int l = threadIdx.x;  // 0..63
  int lr = l & 15, lg = l >> 4;
  const float* src;
  float sc = 1.f;
  if (g < 384) {
    int rt = g >> 3, ks = g & 7;
    src = qkv_w + (size_t)(16 * rt + lr) * 256 + 32 * ks + 8 * lg;
    if (rt < 16) sc = QSCALE * LOG2E;  // fold scale and log2e into q rows
  } else {
    int p = g - 384;
    int rt = p >> 3, ks = p & 7;
    src = proj_w + (size_t)(16 * rt + lr) * 256 + 32 * ks + 8 * lg;
  }
  f32x4 a = *(const f32x4*)(src)*sc;
  f32x4 b = *(const f32x4*)(src + 4) * sc;
  unsigned long long* dst = (unsigned long long*)(ws + (size_t)g * 1024 + l * 16);
  dst[0] = pack4bf(a);
  dst[1] = pack4bf(b);
}

// mb[w][h][64][64] = (mask + rel-pos bias) * log2e, masked cols -> -1e30
__global__ void prep_aux(const float* __restrict__ mask,
                         const float* __restrict__ bias_table,
                         const float* __restrict__ qkv_b,
                         unsigned char* __restrict__ ws) {
  int bid = blockIdx.x, tid = threadIdx.x;
  if (bid < 512) {
    int w = bid >> 3, h = bid & 7;
    float* dst = (float*)(ws + WS_MB) + (size_t)bid * 4096;
    for (int it = 0; it < 16; ++it) {
      int idx = it * 256 + tid;
      int m = idx >> 6, j = idx & 63;
      float v;
      if (j >= 49) {
        v = -1e30f;
      } else {
        float bi = 0.f, mk = 0.f;
        if (m < 49) {
          int rm = m / 7, cm = m % 7, rj = j / 7, cj = j % 7;
          int rpi = (rm - rj + 6) * 13 + (cm - cj + 6);
          bi = bias_table[rpi * 8 + h];
          mk = mask[((size_t)w * 49 + m) * 49 + j];
        }
        v = (mk + bi) * LOG2E;
      }
      dst[idx] = v;
    }
  } else {  // qkv bias: q part prescaled
    float* dst = (float*)(ws + WS_QB);
    for (int i = tid; i < 768; i += 256)
      dst[i] = qkv_b[i] * (i < 256 ? QSCALE * LOG2E : 1.f);
  }
}

// One block = one window, 4 waves (256 thr), 4 passes of 2 heads.
// Wave wv: head-slot hs = wv>>1, m-half s = wv&1; pass p: head h = 2p + hs.
// x fragments live in REGISTERS (xf[2][8], 64 VGPR): Phase B has zero LDS reads.
// bufQ/bufK double-buffered by pass parity; bufP in its own region (no alias),
// so only 3 block barriers per pass. LDS 72.5 KiB -> 2 blocks/CU.
//  [0,32K)        aoR: ao[m][256ch] bf16, byte = m*512 + (2c ^ ((m&7)<<4))
//  (hs,par):      bufQ = 32768 + (2hs+par)*9216 (q [64m][32d] stride 72; then
//                   vT [32d][64tok] stride 128, byte = d*128+((2t)^((d&7)<<4)))
//                 bufK = bufQ + 4608     (k [64m][32d] stride 72)
//  per wave:      bufP = 69632 + wv*1152 ([16m][32j] stride 72)
__global__ __launch_bounds__(256, 2)
void winattn_main(const float* __restrict__ x,
                  const unsigned char* __restrict__ ws,
                  const float* __restrict__ proj_b,
                  float* __restrict__ out) {
  __shared__ __align__(16) unsigned char lds[74240];
  const int tid = threadIdx.x;
  const int wv = tid >> 6, ln = tid & 63;
  const int lr = ln & 15, lg = ln >> 4;
  const int b = blockIdx.x;
  const int w = b & 63;
  const int hs = wv >> 1, s = wv & 1;
  const float* qbs = (const float*)(ws + WS_QB);
  unsigned char* aoR = lds;
  unsigned char* bufP = lds + 69632 + wv * 1152;

  // ---- x fragments -> registers (held for entire kernel); rows >= 49 zero
  bf16x8 xf[2][8];
#pragma unroll
  for (int ti = 0; ti < 2; ++ti) {
    const int row = 16 * (2 * s + ti) + lr;
    const float* xr = x + ((size_t)b * 49 + row) * 256 + 8 * lg;
    const bool val = (row < 49);
#pragma unroll
    for (int ks = 0; ks < 8; ++ks) {
      f32x4 va = {0.f, 0.f, 0.f, 0.f}, vb = {0.f, 0.f, 0.f, 0.f};
      if (val) {
        va = *(const f32x4*)(xr + 32 * ks);
        vb = *(const f32x4*)(xr + 32 * ks + 4);
      }
      u64x2 t2 = {pack4bf(va), pack4bf(vb)};
      xf[ti][ks] = __builtin_bit_cast(bf16x8, t2);
    }
  }

  for (int p = 0; p < 4; ++p) {
    if (p) __syncthreads();  // insurance: prior-pass reads done before restage
    const int par = p & 1;
    unsigned char* bufQ = lds + 32768 + (2 * hs + par) * 9216;  // q, then vT
    unsigned char* bufK = bufQ + 4608;
    const int h = 2 * p + hs;
    const float* mbp = (const float*)(ws + WS_MB) + ((size_t)(w * 8 + h)) * 4096;

    // ---- Phase B: q,k GEMMs (no LDS reads; af from L2-hot ws)
#pragma unroll
    for (int pp = 0; pp < 2; ++pp) {
      unsigned char* dst = (pp == 0 ? bufQ : bufK);
#pragma unroll
      for (int g2 = 0; g2 < 2; ++g2) {
        const int rt = pp * 16 + 2 * h + g2;
        bf16x8 af[8];
#pragma unroll
        for (int ks = 0; ks < 8; ++ks)
          af[ks] = *(const bf16x8*)(ws + (size_t)(rt * 8 + ks) * 1024 + ln * 16);
        f32x4 cc = *(const f32x4*)(qbs + pp * 256 + 32 * h + 16 * g2 + 4 * lg);
#pragma unroll
        for (int ti = 0; ti < 2; ++ti) {
          const int row = 16 * (2 * s + ti) + lr;
          f32x4 a = cc;
#pragma unroll
          for (int ks = 0; ks < 8; ++ks)
            a = __builtin_amdgcn_mfma_f32_16x16x32_bf16(af[ks], xf[ti][ks], a, 0, 0, 0);
          *(unsigned long long*)(dst + row * 72 + 32 * g2 + 8 * lg) = pack4bf(a);
        }
      }
    }
    bf16x8 qf[2];
#pragma unroll
    for (int i = 0; i < 2; ++i)  // own rows -> no barrier needed
      qf[i] = *(const bf16x8*)(bufQ + (lr + 32 * s + 16 * i) * 72 + 16 * lg);
    __syncthreads();  // partner's qf read done before vT clobbers q region

    // v GEMM -> vT into bufQ (q consumed)
#pragma unroll
    for (int g2 = 0; g2 < 2; ++g2) {
      const int rt = 32 + 2 * h + g2;
      bf16x8 af[8];
#pragma unroll
      for (int ks = 0; ks < 8; ++ks)
        af[ks] = *(const bf16x8*)(ws + (size_t)(rt * 8 + ks) * 1024 + ln * 16);
      const float vb = qbs[512 + 32 * h + 16 * g2 + lr];
      f32x4 cc = {vb, vb, vb, vb};
#pragma unroll
      for (int ti = 0; ti < 2; ++ti) {
        const int t = 2 * s + ti;
        f32x4 a = cc;
#pragma unroll
        for (int ks = 0; ks < 8; ++ks)
          a = __builtin_amdgcn_mfma_f32_16x16x32_bf16(xf[ti][ks], af[ks], a, 0, 0, 0);
        const int d = 16 * g2 + lr;
        *(unsigned long long*)(bufQ + d * 128 + ((32 * t + 8 * lg) ^ ((d & 7) << 4))) =
            pack4bf(a);
      }
    }
    __syncthreads();  // k + vT staged pair-wide
    bf16x8 kf[4];
#pragma unroll
    for (int t = 0; t < 4; ++t)
      kf[t] = *(const bf16x8*)(bufK + (lr + 16 * t) * 72 + 16 * lg);

    // ---- Phase C: S^T = K Q^T (C-init = mb), exp2 softmax, PV
    float sm[2] = {0.f, 0.f};
    f32x4 oacc[2][2];
#pragma unroll
    for (int dt = 0; dt < 2; ++dt)
#pragma unroll
      for (int i = 0; i < 2; ++i) oacc[dt][i] = {0.f, 0.f, 0.f, 0.f};
#pragma unroll
    for (int jh = 0; jh < 2; ++jh) {
      bf16x8 vf[2];
#pragma unroll
      for (int dt = 0; dt < 2; ++dt) {
        const int d = lr + 16 * dt;
        vf[dt] = *(const bf16x8*)(bufQ + d * 128 + ((64 * jh + 16 * lg) ^ ((d & 7) << 4)));
      }
#pragma unroll
      for (int i = 0; i < 2; ++i) {
        const int m = lr + 32 * s + 16 * i;
#pragma unroll
        for (int jt2 = 0; jt2 < 2; ++jt2) {
          const int jt = 2 * jh + jt2;
          f32x4 mk = *(const f32x4*)(mbp + m * 64 + 16 * jt + 4 * lg);
          f32x4 sv = __builtin_amdgcn_mfma_f32_16x16x32_bf16(kf[jt], qf[i], mk, 0, 0, 0);
#pragma unroll
          for (int r2 = 0; r2 < 4; ++r2) {
            float e = __builtin_amdgcn_exp2f(sv[r2]);
            sv[r2] = e;
            sm[i] += e;
          }
          *(unsigned long long*)(bufP + lr * 72 + 32 * jt2 + 8 * lg) = pack4bf(sv);
        }
        bf16x8 pf = *(const bf16x8*)(bufP + lr * 72 + 16 * lg);
#pragma unroll
        for (int dt = 0; dt < 2; ++dt)
          oacc[dt][i] = __builtin_amdgcn_mfma_f32_16x16x32_bf16(vf[dt], pf, oacc[dt][i], 0, 0, 0);
      }
    }
    // normalize + write ao for this head into aoR
#pragma unroll
    for (int i = 0; i < 2; ++i) {
      float t = sm[i];
      t += __shfl_xor(t, 16);
      t += __shfl_xor(t, 32);
      const float inv = 1.f / t;
      const int m = lr + 32 * s + 16 * i;
#pragma unroll
      for (int dt = 0; dt < 2; ++dt)
        *(unsigned long long*)(aoR + m * 512 +
                               ((64 * h + 32 * dt + 8 * lg) ^ ((m & 7) << 4))) =
            pack4bf(oacc[dt][i] * inv);
    }
  }
  __syncthreads();  // all heads' ao staged

  // ---- Phase D: proj^T[o][m] = sum_c Wp[o][c] * ao[m][c]
  const unsigned char* wsP = ws + WS_PROJ;
#pragma unroll
  for (int tt = 0; tt < 4; ++tt) {
    const int m = lr + 16 * tt;
    bf16x8 aof[8];
#pragma unroll
    for (int ks = 0; ks < 8; ++ks)
      aof[ks] = *(const bf16x8*)(aoR + m * 512 + ((64 * ks + 16 * lg) ^ ((m & 7) << 4)));
#pragma unroll
    for (int i2 = 0; i2 < 4; ++i2) {
      const int mt = 4 * wv + i2;
      bf16x8 af[8];
#pragma unroll
      for (int ks = 0; ks < 8; ++ks)
        af[ks] = *(const bf16x8*)(wsP + (size_t)(mt * 8 + ks) * 1024 + ln * 16);
      f32x4 acc = {0.f, 0.f, 0.f, 0.f};
#pragma unroll
      for (int ks = 0; ks < 8; ++ks)
        acc = __builtin_amdgcn_mfma_f32_16x16x32_bf16(af[ks], aof[ks], acc, 0, 0, 0);
      if (m < 49) {
        f32x4 pb = *(const f32x4*)(proj_b + 16 * mt + 4 * lg);
        acc += pb;
        *(f32x4*)(out + ((size_t)b * 49 + m) * 256 + 16 * mt + 4 * lg) = acc;
      }
    }
  }
}

extern "C" void kernel_launch(void* const* d_in, const int* in_sizes, int n_in,
                              void* d_out, int out_size, void* d_ws, size_t ws_size,
                              hipStream_t stream) {
  const float* x = (const float*)d_in[0];
  const float* mask = (const float*)d_in[1];
  const float* qkv_w = (const float*)d_in[2];
  const float* qkv_b = (const float*)d_in[3];
  const float* proj_w = (const float*)d_in[4];
  const float* proj_b = (const float*)d_in[5];
  const float* bias_table = (const float*)d_in[6];
  unsigned char* ws = (unsigned char*)d_ws;
  float* out = (float*)d_out;

  prep_weights<<<512, 64, 0, stream>>>(qkv_w, proj_w, ws);
  prep_aux<<<513, 256, 0, stream>>>(mask, bias_table, qkv_b, ws);
  winattn_main<<<4096, 256, 0, stream>>>(x, ws, proj_b, out);
}